// Round 4
// baseline (117.128 us; speedup 1.0000x reference)
//
#include <hip/hip_runtime.h>
#include <cstdint>
#include <cstddef>

typedef short bf16x8 __attribute__((ext_vector_type(8)));
typedef float f32x4 __attribute__((ext_vector_type(4)));

#define BN 8
#define TN 2048
#define CN 1024
#define HN 64

__device__ __forceinline__ unsigned short f2bf(float f) {
    unsigned int u = __float_as_uint(f);
    u += 0x7fffu + ((u >> 16) & 1u);
    return (unsigned short)(u >> 16);
}

// Build Wct[n][c] (bf16), n in [0,192): n<64 = Wq col h (pre-scaled by 0.125*log2e),
// 64..127 = Wk col, 128..191 = Wv col.  Source W is [C][H] row-major.
__global__ __launch_bounds__(256) void wconv_kernel(const float* __restrict__ Wq,
                                                    const float* __restrict__ Wk,
                                                    const float* __restrict__ Wv,
                                                    unsigned short* __restrict__ Wct) {
    int idx = blockIdx.x * 256 + threadIdx.x;   // 0..196607
    int n = idx >> 10;
    int c = idx & 1023;
    int m = n >> 6;
    int h = n & 63;
    const float* W = (m == 0) ? Wq : ((m == 1) ? Wk : Wv);
    float v = W[c * 64 + h];
    if (m == 0) v *= 0.18033688011112042f;  // (1/sqrt(64)) * log2(e)
    Wct[idx] = f2bf(v);
}

// Fused QKV projection v3: W staged in LDS (the reused operand), X streamed.
// 512 blocks x 256 threads (4 waves).  Block = 32 rows of X; wave = 48-col
// N-quarter x both 16-row M-tiles.  K-chunks of 128: Ws[192][128] bf16,
// XOR-swizzled ((row&15)<<4) over each 256B row.
__global__ __launch_bounds__(256) void proj_kernel(const float* __restrict__ X,
                                                   const unsigned short* __restrict__ Wct,
                                                   unsigned short* __restrict__ Qs,
                                                   unsigned short* __restrict__ Ks,
                                                   unsigned short* __restrict__ Vt) {
    __shared__ short Ws[192 * 128];   // 48 KB
    char* WsB = (char*)Ws;

    const int tid = threadIdx.x;
    const int w   = tid >> 6;       // N-quarter 0..3
    const int l   = tid & 63;
    const int lq  = l & 15;
    const int lg  = l >> 4;
    const int rowbase = blockIdx.x * 32;

    const f32x4 zero4 = {0.f, 0.f, 0.f, 0.f};
    f32x4 acc[2][3];
    #pragma unroll
    for (int mi = 0; mi < 2; ++mi)
        #pragma unroll
        for (int j = 0; j < 3; ++j) acc[mi][j] = zero4;

    const float* xb0 = X + (size_t)(rowbase + lq) * CN;
    const float* xb1 = X + (size_t)(rowbase + 16 + lq) * CN;

    // B-fragment LDS byte addresses (chunk-local), per j
    int baddr[3];
    #pragma unroll
    for (int j = 0; j < 3; ++j) {
        const int n = w * 48 + j * 16 + lq;
        baddr[j] = n * 256 + (((lg * 16)) ^ ((n & 15) << 4));
    }

    for (int ch = 0; ch < 8; ++ch) {
        __syncthreads();   // protect Ws from previous chunk's readers
        // cooperative stage: 24576 elems / 256 threads = 96 = 12 x bf16x8
        #pragma unroll
        for (int it = 0; it < 12; ++it) {
            const int e = it * 2048 + tid * 8;
            const int row = e >> 7;
            const int col = e & 127;
            bf16x8 t = *(const bf16x8*)(Wct + (size_t)row * CN + ch * 128 + col);
            *(bf16x8*)(WsB + (row * 256 + ((col * 2) ^ ((row & 15) << 4)))) = t;
        }
        __syncthreads();

        // issue all X loads for this chunk (16 float4, independent)
        float4 xf[4][2][2];
        #pragma unroll
        for (int kk = 0; kk < 4; ++kk) {
            const int kg = ch * 128 + kk * 32 + lg * 8;
            xf[kk][0][0] = *(const float4*)(xb0 + kg);
            xf[kk][0][1] = *(const float4*)(xb0 + kg + 4);
            xf[kk][1][0] = *(const float4*)(xb1 + kg);
            xf[kk][1][1] = *(const float4*)(xb1 + kg + 4);
        }

        #pragma unroll
        for (int kk = 0; kk < 4; ++kk) {
            bf16x8 a[2];
            #pragma unroll
            for (int mi = 0; mi < 2; ++mi) {
                bf16x8 t;
                t[0] = (short)f2bf(xf[kk][mi][0].x); t[1] = (short)f2bf(xf[kk][mi][0].y);
                t[2] = (short)f2bf(xf[kk][mi][0].z); t[3] = (short)f2bf(xf[kk][mi][0].w);
                t[4] = (short)f2bf(xf[kk][mi][1].x); t[5] = (short)f2bf(xf[kk][mi][1].y);
                t[6] = (short)f2bf(xf[kk][mi][1].z); t[7] = (short)f2bf(xf[kk][mi][1].w);
                a[mi] = t;
            }
            bf16x8 b[3];
            #pragma unroll
            for (int j = 0; j < 3; ++j)
                b[j] = *(const bf16x8*)(WsB + (baddr[j] + kk * 64));  // kk*64 stays in swizzle window
            // note: kk*64 must be XORed consistently: baddr already has lg*16^swz;
            // kk*64 occupies bits 6-7, swz bits 4-7 -> recompute properly:
            #pragma unroll
            for (int j = 0; j < 3; ++j) {
                const int n = w * 48 + j * 16 + lq;
                b[j] = *(const bf16x8*)(WsB + (n * 256 + ((kk * 64 + lg * 16) ^ ((n & 15) << 4))));
            }
            acc[0][0] = __builtin_amdgcn_mfma_f32_16x16x32_bf16(a[0], b[0], acc[0][0], 0, 0, 0);
            acc[1][0] = __builtin_amdgcn_mfma_f32_16x16x32_bf16(a[1], b[0], acc[1][0], 0, 0, 0);
            acc[0][1] = __builtin_amdgcn_mfma_f32_16x16x32_bf16(a[0], b[1], acc[0][1], 0, 0, 0);
            acc[1][1] = __builtin_amdgcn_mfma_f32_16x16x32_bf16(a[1], b[1], acc[1][1], 0, 0, 0);
            acc[0][2] = __builtin_amdgcn_mfma_f32_16x16x32_bf16(a[0], b[2], acc[0][2], 0, 0, 0);
            acc[1][2] = __builtin_amdgcn_mfma_f32_16x16x32_bf16(a[1], b[2], acc[1][2], 0, 0, 0);
        }
    }

    // D layout: col = lane&15 (W col), row = 4*(lane>>4) + reg (X row)
    #pragma unroll
    for (int j = 0; j < 3; ++j) {
        const int col = w * 48 + j * 16 + lq;
        const int mtx = col >> 6;          // 0=Q, 1=K, 2=V
        const int h   = col & 63;
        #pragma unroll
        for (int mi = 0; mi < 2; ++mi) {
            #pragma unroll
            for (int i = 0; i < 4; ++i) {
                const int g = rowbase + mi * 16 + 4 * lg + i;
                const unsigned short val = f2bf(acc[mi][j][i]);
                if (mtx == 0) {
                    Qs[(size_t)g * 64 + h] = val;
                } else if (mtx == 1) {
                    Ks[(size_t)g * 64 + h] = val;
                } else {
                    const int bb = g >> 11, t = g & 2047;
                    Vt[(size_t)((bb << 6) + h) * 2048 + t] = val;
                }
            }
        }
    }
}

// Block-cooperative causal flash attention (unchanged from round 3).
// Block = (batch, q-tile pair {127-pr, pr}) -> exactly 65 key-tiles per block.
__global__ __launch_bounds__(256) void attn_kernel(const unsigned short* __restrict__ Qs,
                                                   const unsigned short* __restrict__ Ks,
                                                   const unsigned short* __restrict__ Vt,
                                                   float* __restrict__ Out) {
    __shared__ float lm[2][4][16];
    __shared__ float ll[2][4][16];
    __shared__ float facc[2][4][1024];

    const int tid = threadIdx.x;
    const int w  = tid >> 6;
    const int l  = tid & 63;
    const int lq = l & 15;
    const int lg = l >> 4;
    const int bid = blockIdx.x;
    const int b  = bid >> 6;
    const int pr = bid & 63;

    const unsigned short* Qb = Qs + (size_t)b * TN * 64;
    const unsigned short* Kb = Ks + (size_t)b * TN * 64;
    const unsigned short* Vb = Vt + (size_t)b * 64 * TN;

    int koff[4];
    #pragma unroll
    for (int fa = 0; fa < 2; ++fa)
        #pragma unroll
        for (int ks = 0; ks < 2; ++ks)
            koff[fa * 2 + ks] = (fa * 16 + lq) * 64 + ks * 32 + lg * 8;
    int voff[4];
    #pragma unroll
    for (int nf = 0; nf < 4; ++nf)
        voff[nf] = (nf * 16 + lq) * 2048 + 4 * lg;

    const f32x4 zero4 = {0.f, 0.f, 0.f, 0.f};

    #pragma unroll
    for (int X = 0; X < 2; ++X) {
        const int qt = (X == 0) ? (127 - pr) : pr;
        const int q0 = qt * 16;
        const int nt = (qt >> 1) + 1;

        bf16x8 qa0 = *(const bf16x8*)(Qb + (size_t)(q0 + lq) * 64 + 0 * 32 + lg * 8);
        bf16x8 qa1 = *(const bf16x8*)(Qb + (size_t)(q0 + lq) * 64 + 1 * 32 + lg * 8);

        f32x4 acc[4] = {zero4, zero4, zero4, zero4};
        float mrow = -1e30f;
        float lrow = 0.f;

        bf16x8 Kc[4], Vc[4], Kn[4], Vn[4];
        int kt = w;
        if (kt < nt) {
            const size_t kb = (size_t)kt * 2048;
            #pragma unroll
            for (int i = 0; i < 4; ++i)
                Kc[i] = *(const bf16x8*)(Kb + kb + koff[i]);
            #pragma unroll
            for (int nf = 0; nf < 4; ++nf) {
                union { bf16x8 v; ushort4 h[2]; } u;
                u.h[0] = *(const ushort4*)(Vb + voff[nf] + kt * 32);
                u.h[1] = *(const ushort4*)(Vb + voff[nf] + kt * 32 + 16);
                Vc[nf] = u.v;
            }
        }

        for (; kt < nt; kt += 4) {
            const int ktn = kt + 4;
            if (ktn < nt) {
                const size_t kb = (size_t)ktn * 2048;
                #pragma unroll
                for (int i = 0; i < 4; ++i)
                    Kn[i] = *(const bf16x8*)(Kb + kb + koff[i]);
                #pragma unroll
                for (int nf = 0; nf < 4; ++nf) {
                    union { bf16x8 v; ushort4 h[2]; } u;
                    u.h[0] = *(const ushort4*)(Vb + voff[nf] + ktn * 32);
                    u.h[1] = *(const ushort4*)(Vb + voff[nf] + ktn * 32 + 16);
                    Vn[nf] = u.v;
                }
            }

            const int key0 = kt * 32;
            f32x4 s[2];
            s[0] = __builtin_amdgcn_mfma_f32_16x16x32_bf16(Kc[0], qa0, zero4, 0, 0, 0);
            s[0] = __builtin_amdgcn_mfma_f32_16x16x32_bf16(Kc[1], qa1, s[0], 0, 0, 0);
            s[1] = __builtin_amdgcn_mfma_f32_16x16x32_bf16(Kc[2], qa0, zero4, 0, 0, 0);
            s[1] = __builtin_amdgcn_mfma_f32_16x16x32_bf16(Kc[3], qa1, s[1], 0, 0, 0);

            if (kt == nt - 1) {
                const int q = q0 + lq;
                #pragma unroll
                for (int fa = 0; fa < 2; ++fa)
                    #pragma unroll
                    for (int r = 0; r < 4; ++r) {
                        const int key = key0 + fa * 16 + 4 * lg + r;
                        if (key > q) s[fa][r] = -1e30f;
                    }
            }

            float m1 = fmaxf(fmaxf(s[0][0], s[0][1]), s[0][2]);
            float m2 = fmaxf(fmaxf(s[0][3], s[1][0]), s[1][1]);
            float m3 = fmaxf(fmaxf(s[1][2], s[1][3]), m1);
            float tm = fmaxf(m2, m3);
            tm = fmaxf(tm, __shfl_xor(tm, 16));
            tm = fmaxf(tm, __shfl_xor(tm, 32));

            if (!__all(tm <= mrow + 8.0f)) {
                const float mnew = fmaxf(mrow, tm);
                const float cc = __builtin_amdgcn_exp2f(mrow - mnew);
                lrow *= cc;
                float cb[4];
                #pragma unroll
                for (int i = 0; i < 4; ++i) cb[i] = __shfl(cc, 4 * lg + i);
                #pragma unroll
                for (int nf = 0; nf < 4; ++nf)
                    #pragma unroll
                    for (int i = 0; i < 4; ++i) acc[nf][i] *= cb[i];
                mrow = mnew;
            }

            float p[2][4];
            float psum = 0.f;
            #pragma unroll
            for (int fa = 0; fa < 2; ++fa)
                #pragma unroll
                for (int r = 0; r < 4; ++r) {
                    p[fa][r] = __builtin_amdgcn_exp2f(s[fa][r] - mrow);
                    psum += p[fa][r];
                }
            psum += __shfl_xor(psum, 16);
            psum += __shfl_xor(psum, 32);
            lrow += psum;

            bf16x8 pa;
            pa[0] = (short)f2bf(p[0][0]); pa[1] = (short)f2bf(p[0][1]);
            pa[2] = (short)f2bf(p[0][2]); pa[3] = (short)f2bf(p[0][3]);
            pa[4] = (short)f2bf(p[1][0]); pa[5] = (short)f2bf(p[1][1]);
            pa[6] = (short)f2bf(p[1][2]); pa[7] = (short)f2bf(p[1][3]);

            acc[0] = __builtin_amdgcn_mfma_f32_16x16x32_bf16(pa, Vc[0], acc[0], 0, 0, 0);
            acc[1] = __builtin_amdgcn_mfma_f32_16x16x32_bf16(pa, Vc[1], acc[1], 0, 0, 0);
            acc[2] = __builtin_amdgcn_mfma_f32_16x16x32_bf16(pa, Vc[2], acc[2], 0, 0, 0);
            acc[3] = __builtin_amdgcn_mfma_f32_16x16x32_bf16(pa, Vc[3], acc[3], 0, 0, 0);

            #pragma unroll
            for (int i = 0; i < 4; ++i) { Kc[i] = Kn[i]; Vc[i] = Vn[i]; }
        }

        if (lg == 0) {
            lm[X][w][lq] = mrow;
            ll[X][w][lq] = lrow;
        }
        #pragma unroll
        for (int nf = 0; nf < 4; ++nf)
            #pragma unroll
            for (int i = 0; i < 4; ++i)
                facc[X][w][(4 * lg + i) * 64 + nf * 16 + lq] = acc[nf][i];
    }

    __syncthreads();

    #pragma unroll
    for (int X = 0; X < 2; ++X) {
        const int qt = (X == 0) ? (127 - pr) : pr;
        const int q0 = qt * 16;
        #pragma unroll
        for (int ii = 0; ii < 4; ++ii) {
            const int e = tid + ii * 256;
            const int q = e >> 6;
            const int h = e & 63;
            const float M = fmaxf(fmaxf(lm[X][0][q], lm[X][1][q]),
                                  fmaxf(lm[X][2][q], lm[X][3][q]));
            float L = 0.f, O = 0.f;
            #pragma unroll
            for (int c = 0; c < 4; ++c) {
                const float wgt = __builtin_amdgcn_exp2f(lm[X][c][q] - M);
                L += wgt * ll[X][c][q];
                O += wgt * facc[X][c][q * 64 + h];
            }
            Out[((size_t)b * TN + q0 + q) * 64 + h] = O / L;
        }
    }
}

extern "C" void kernel_launch(void* const* d_in, const int* in_sizes, int n_in,
                              void* d_out, int out_size, void* d_ws, size_t ws_size,
                              hipStream_t stream) {
    const float* X  = (const float*)d_in[0];
    const float* Wq = (const float*)d_in[1];
    const float* Wk = (const float*)d_in[2];
    const float* Wv = (const float*)d_in[3];
    float* Out = (float*)d_out;

    char* ws = (char*)d_ws;
    unsigned short* Wct = (unsigned short*)(ws);                 // 384 KB (pad 512 KB)
    unsigned short* Qs  = (unsigned short*)(ws + (512u << 10));  // 2 MB
    unsigned short* Ks  = Qs + (size_t)16384 * 64;               // 2 MB
    unsigned short* Vt  = Ks + (size_t)16384 * 64;               // 2 MB

    hipLaunchKernelGGL(wconv_kernel, dim3(768), dim3(256), 0, stream, Wq, Wk, Wv, Wct);
    hipLaunchKernelGGL(proj_kernel,  dim3(512), dim3(256), 0, stream, X, Wct, Qs, Ks, Vt);
    hipLaunchKernelGGL(attn_kernel,  dim3(512), dim3(256), 0, stream, Qs, Ks, Vt, Out);
}